// Round 2
// baseline (1834.767 us; speedup 1.0000x reference)
//
#include <hip/hip_runtime.h>

// ---------------------------------------------------------------------------
// RGCN (basis decomposition, 2 layers) + mean-pool.
// Edge phase: relation-bucketed edge tiles -> bf16 MFMA (16x16x32) -> f32
// atomic scatter. Self-loops via f32 readlane GEMV. Output mean-pool.
//
// ws layout (bytes):
//   W1f   us[8*4096]   @ 0           (65536)   B-frags of W1, bf16
//   W2f   us[8*1024]   @ 65536       (16384)   B-frags of W2, bf16
//   agg1  f32[N*64]    @ 81920       (25,600,000)  (becomes h in-place)
//   agg2  f32[N*16]    @ 25,681,920  (6,400,000)
//   order int[E+128]   @ 32,081,920  (4,000,512)
//   cnt   int[16]      @ 36,082,432  (cnt[0..7], cursor[8..15])
//   offs  int[9]       @ 36,082,496
//   start int[65]      @ 36,082,560
// total ~36.1 MB
// ---------------------------------------------------------------------------

typedef __attribute__((ext_vector_type(8))) short bf16x8;
typedef __attribute__((ext_vector_type(4))) float f32x4;

__device__ __forceinline__ unsigned short f2bf(float f) {
    unsigned u = __float_as_uint(f);
    unsigned r = u + 0x7FFFu + ((u >> 16) & 1u);   // RNE
    return (unsigned short)(r >> 16);
}

__device__ __forceinline__ float bcast(float v, int l) {
    return __uint_as_float(__builtin_amdgcn_readlane(__float_as_uint(v), l));
}

// ---- weights: W_r = sum_b coeff[r,b]*bases[b], written in B-fragment order.
// Frag convention (16x16x32 bf16): lane l holds B[k = kt*32+(l>>4)*8+j][n],
// n = nt*16+(l&15), j=0..7 contiguous.  Same k-order is used for A loads.
__global__ __launch_bounds__(256) void k_weights(
    const float* __restrict__ bases1, const float* __restrict__ coeff1,
    const float* __restrict__ bases2, const float* __restrict__ coeff2,
    unsigned short* __restrict__ W1f, unsigned short* __restrict__ W2f,
    int* __restrict__ cnt) {
    int r = blockIdx.x;
    int tid = threadIdx.x;
    if (r == 0 && tid < 16) cnt[tid] = 0;
    float c1[8], c2[8];
#pragma unroll
    for (int b = 0; b < 8; ++b) { c1[b] = coeff1[r * 8 + b]; c2[b] = coeff2[r * 8 + b]; }
    for (int idx = tid; idx < 4096; idx += 256) {
        int j = idx & 7, lane = (idx >> 3) & 63, nt = (idx >> 9) & 3, kt = idx >> 11;
        int i = kt * 32 + ((lane >> 4) << 3) + j;
        int jo = nt * 16 + (lane & 15);
        float s = 0.f;
#pragma unroll
        for (int b = 0; b < 8; ++b) s = fmaf(c1[b], bases1[b * 4096 + i * 64 + jo], s);
        W1f[r * 4096 + idx] = f2bf(s);
    }
    for (int idx = tid; idx < 1024; idx += 256) {
        int j = idx & 7, lane = (idx >> 3) & 63, kt = idx >> 9;
        int i = kt * 32 + ((lane >> 4) << 3) + j;
        int jo = lane & 15;
        float s = 0.f;
#pragma unroll
        for (int b = 0; b < 8; ++b) s = fmaf(c2[b], bases2[b * 1024 + i * 16 + jo], s);
        W2f[r * 1024 + idx] = f2bf(s);
    }
}

// ---- histogram of etypes (register counts -> LDS -> global)
__global__ __launch_bounds__(256) void k_hist(
    const int* __restrict__ et, int* __restrict__ cnt, int nE) {
    __shared__ int sm[8];
    if (threadIdx.x < 8) sm[threadIdx.x] = 0;
    __syncthreads();
    int l0 = 0, l1 = 0, l2 = 0, l3 = 0, l4 = 0, l5 = 0, l6 = 0, l7 = 0;
    int stride = gridDim.x * blockDim.x;
    for (int e = blockIdx.x * blockDim.x + threadIdx.x; e < nE; e += stride) {
        int t = et[e];
        l0 += (t == 0); l1 += (t == 1); l2 += (t == 2); l3 += (t == 3);
        l4 += (t == 4); l5 += (t == 5); l6 += (t == 6); l7 += (t == 7);
    }
    if (l0) atomicAdd(&sm[0], l0); if (l1) atomicAdd(&sm[1], l1);
    if (l2) atomicAdd(&sm[2], l2); if (l3) atomicAdd(&sm[3], l3);
    if (l4) atomicAdd(&sm[4], l4); if (l5) atomicAdd(&sm[5], l5);
    if (l6) atomicAdd(&sm[6], l6); if (l7) atomicAdd(&sm[7], l7);
    __syncthreads();
    if (threadIdx.x < 8) atomicAdd(&cnt[threadIdx.x], sm[threadIdx.x]);
}

// ---- prefix offsets (16-aligned), init cursors, write pad sentinels
__global__ void k_scan(int* __restrict__ cnt, int* __restrict__ offs,
                       int* __restrict__ order) {
    if (threadIdx.x == 0 && blockIdx.x == 0) {
        int o = 0;
        for (int r = 0; r < 8; ++r) {
            offs[r] = o;
            cnt[8 + r] = o;                    // cursor
            int a = (cnt[r] + 15) & ~15;
            for (int p = cnt[r]; p < a; ++p) order[o + p] = -1;
            o += a;
        }
        offs[8] = o;
    }
}

// ---- scatter edge ids into relation buckets (wave-aggregated cursors)
__global__ __launch_bounds__(256) void k_scatter(
    const int* __restrict__ et, int* __restrict__ cursor,
    int* __restrict__ order, int nE) {
    int lane = threadIdx.x & 63;
    int gw = (int)((blockIdx.x * blockDim.x + threadIdx.x) >> 6);
    int nW = (int)((gridDim.x * blockDim.x) >> 6);
    for (int c = gw * 64; c < nE; c += nW * 64) {
        int e = c + lane;
        bool act = e < nE;
        int r = act ? et[e] : -1;
        int pos = 0;
        unsigned long long below = (lane == 63) ? ~0ull >> 1 : ((1ull << lane) - 1);
#pragma unroll
        for (int rr = 0; rr < 8; ++rr) {
            unsigned long long m = __ballot(r == rr);
            if (r == rr) {
                int leader = __ffsll((long long)m) - 1;
                int rank = __popcll(m & below);
                int base = 0;
                if (lane == leader) base = atomicAdd(&cursor[rr], __popcll(m));
                base = __shfl(base, leader, 64);
                pos = base + rank;
            }
        }
        if (act) order[pos] = e;
    }
}

// ---- self-loop layer1: agg1[n][j] = bias1[j] + sum_i x[n][i]*wself1[i][j]
__global__ __launch_bounds__(256) void k_lin1(
    const float* __restrict__ x, const float* __restrict__ wself,
    const float* __restrict__ bias, float* __restrict__ agg, int nNodes) {
    int lane = threadIdx.x & 63;
    int gw = (int)((blockIdx.x * blockDim.x + threadIdx.x) >> 6);
    int nW = (int)((gridDim.x * blockDim.x) >> 6);
    float w[64];
#pragma unroll
    for (int i = 0; i < 64; ++i) w[i] = wself[i * 64 + lane];
    float bj = bias[lane];
    for (int n = gw; n < nNodes; n += nW) {
        float xv = x[n * 64 + lane];
        float a0 = 0.f, a1 = 0.f, a2 = 0.f, a3 = 0.f;
#pragma unroll
        for (int i = 0; i < 64; i += 4) {
            a0 = fmaf(bcast(xv, i + 0), w[i + 0], a0);
            a1 = fmaf(bcast(xv, i + 1), w[i + 1], a1);
            a2 = fmaf(bcast(xv, i + 2), w[i + 2], a2);
            a3 = fmaf(bcast(xv, i + 3), w[i + 3], a3);
        }
        agg[n * 64 + lane] = bj + ((a0 + a1) + (a2 + a3));
    }
}

// ---- edge GEMM layer1: 16-edge tiles, A = gathered x rows (bf16), B = W_r
__global__ __launch_bounds__(256) void k_edgemm1(
    const float* __restrict__ x, const int* __restrict__ src,
    const int* __restrict__ dst, const int* __restrict__ order,
    const int* __restrict__ offs, const unsigned short* __restrict__ W1f,
    float* __restrict__ agg) {
    int lane = threadIdx.x & 63;
    int wid = (int)(threadIdx.x >> 6);
    int tile = blockIdx.x * 4 + wid;
    int t16 = tile * 16;
    if (t16 >= offs[8]) return;
    int r = 0;
#pragma unroll
    for (int q = 1; q < 8; ++q) r += (t16 >= offs[q]);
    const unsigned short* Wf = W1f + r * 4096;
    bf16x8 b[2][4];
#pragma unroll
    for (int kt = 0; kt < 2; ++kt)
#pragma unroll
        for (int nt = 0; nt < 4; ++nt)
            b[kt][nt] = *(const bf16x8*)(Wf + (kt * 4 + nt) * 512 + lane * 8);
    int idxA = order[t16 + (lane & 15)];
    int sA = idxA >= 0 ? src[idxA] : 0;
    const float* xrow = x + (size_t)sA * 64 + ((lane >> 4) << 3);
    bf16x8 a[2];
#pragma unroll
    for (int kt = 0; kt < 2; ++kt) {
        f32x4 u0 = *(const f32x4*)(xrow + kt * 32);
        f32x4 u1 = *(const f32x4*)(xrow + kt * 32 + 4);
        bf16x8 t;
        t[0] = (short)f2bf(u0[0]); t[1] = (short)f2bf(u0[1]);
        t[2] = (short)f2bf(u0[2]); t[3] = (short)f2bf(u0[3]);
        t[4] = (short)f2bf(u1[0]); t[5] = (short)f2bf(u1[1]);
        t[6] = (short)f2bf(u1[2]); t[7] = (short)f2bf(u1[3]);
        a[kt] = t;
    }
    f32x4 z = {0.f, 0.f, 0.f, 0.f};
    f32x4 acc[4] = {z, z, z, z};
#pragma unroll
    for (int kt = 0; kt < 2; ++kt)
#pragma unroll
        for (int nt = 0; nt < 4; ++nt)
            acc[nt] = __builtin_amdgcn_mfma_f32_16x16x32_bf16(a[kt], b[kt][nt], acc[nt], 0, 0, 0);
#pragma unroll
    for (int reg = 0; reg < 4; ++reg) {
        int row = ((lane >> 4) << 2) + reg;
        int idxD = order[t16 + row];
        if (idxD < 0) continue;
        int d = dst[idxD];
        float* ap = agg + (size_t)d * 64 + (lane & 15);
        atomicAdd(ap + 0,  acc[0][reg]);
        atomicAdd(ap + 16, acc[1][reg]);
        atomicAdd(ap + 32, acc[2][reg]);
        atomicAdd(ap + 48, acc[3][reg]);
    }
}

// ---- relu + self-loop layer2; h kept f32 in-place in agg1
__global__ __launch_bounds__(256) void k_lin2(
    float* __restrict__ agg1, const float* __restrict__ wself,
    const float* __restrict__ bias, float* __restrict__ agg2, int nNodes) {
    int lane = threadIdx.x & 63;
    int j = lane & 15;
    int gw = (int)((blockIdx.x * blockDim.x + threadIdx.x) >> 6);
    int nW = (int)((gridDim.x * blockDim.x) >> 6);
    float w[64];
#pragma unroll
    for (int i = 0; i < 64; ++i) w[i] = wself[i * 16 + j];
    float bj = bias[j];
    for (int n = gw; n < nNodes; n += nW) {
        float hv = fmaxf(agg1[n * 64 + lane], 0.f);
        agg1[n * 64 + lane] = hv;
        float a0 = 0.f, a1 = 0.f, a2 = 0.f, a3 = 0.f;
#pragma unroll
        for (int i = 0; i < 64; i += 4) {
            a0 = fmaf(bcast(hv, i + 0), w[i + 0], a0);
            a1 = fmaf(bcast(hv, i + 1), w[i + 1], a1);
            a2 = fmaf(bcast(hv, i + 2), w[i + 2], a2);
            a3 = fmaf(bcast(hv, i + 3), w[i + 3], a3);
        }
        if (lane < 16) agg2[n * 16 + lane] = bj + ((a0 + a1) + (a2 + a3));
    }
}

// ---- edge GEMM layer2: N=16 output cols
__global__ __launch_bounds__(256) void k_edgemm2(
    const float* __restrict__ h, const int* __restrict__ src,
    const int* __restrict__ dst, const int* __restrict__ order,
    const int* __restrict__ offs, const unsigned short* __restrict__ W2f,
    float* __restrict__ agg2) {
    int lane = threadIdx.x & 63;
    int wid = (int)(threadIdx.x >> 6);
    int tile = blockIdx.x * 4 + wid;
    int t16 = tile * 16;
    if (t16 >= offs[8]) return;
    int r = 0;
#pragma unroll
    for (int q = 1; q < 8; ++q) r += (t16 >= offs[q]);
    const unsigned short* Wf = W2f + r * 1024;
    bf16x8 b[2];
    b[0] = *(const bf16x8*)(Wf + lane * 8);
    b[1] = *(const bf16x8*)(Wf + 512 + lane * 8);
    int idxA = order[t16 + (lane & 15)];
    int sA = idxA >= 0 ? src[idxA] : 0;
    const float* hrow = h + (size_t)sA * 64 + ((lane >> 4) << 3);
    bf16x8 a[2];
#pragma unroll
    for (int kt = 0; kt < 2; ++kt) {
        f32x4 u0 = *(const f32x4*)(hrow + kt * 32);
        f32x4 u1 = *(const f32x4*)(hrow + kt * 32 + 4);
        bf16x8 t;
        t[0] = (short)f2bf(u0[0]); t[1] = (short)f2bf(u0[1]);
        t[2] = (short)f2bf(u0[2]); t[3] = (short)f2bf(u0[3]);
        t[4] = (short)f2bf(u1[0]); t[5] = (short)f2bf(u1[1]);
        t[6] = (short)f2bf(u1[2]); t[7] = (short)f2bf(u1[3]);
        a[kt] = t;
    }
    f32x4 acc = {0.f, 0.f, 0.f, 0.f};
    acc = __builtin_amdgcn_mfma_f32_16x16x32_bf16(a[0], b[0], acc, 0, 0, 0);
    acc = __builtin_amdgcn_mfma_f32_16x16x32_bf16(a[1], b[1], acc, 0, 0, 0);
#pragma unroll
    for (int reg = 0; reg < 4; ++reg) {
        int row = ((lane >> 4) << 2) + reg;
        int idxD = order[t16 + row];
        if (idxD < 0) continue;
        int d = dst[idxD];
        atomicAdd(agg2 + (size_t)d * 16 + (lane & 15), acc[reg]);
    }
}

__global__ void k_bounds(const int* __restrict__ gid, int* __restrict__ start, int nNodes) {
    int t = blockIdx.x * blockDim.x + threadIdx.x;
    if (t > 64) return;
    int lo = 0, hi = nNodes;
    while (lo < hi) {
        int mid = (lo + hi) >> 1;
        if (gid[mid] < t) lo = mid + 1; else hi = mid;
    }
    start[t] = lo;
}

__global__ __launch_bounds__(256) void k_pool(
    const float* __restrict__ agg2, const int* __restrict__ start,
    float* __restrict__ out) {
    __shared__ float sm[256];
    int g = blockIdx.x;
    int t = threadIdx.x;
    int c = t & 15, idx = t >> 4;
    int s0 = start[g], s1 = start[g + 1];
    float acc = 0.f;
    for (int n = s0 + idx; n < s1; n += 16) acc += fmaxf(agg2[n * 16 + c], 0.f);
    sm[t] = acc;
    __syncthreads();
#pragma unroll
    for (int off = 128; off >= 16; off >>= 1) {
        if (t < off) sm[t] += sm[t + off];
        __syncthreads();
    }
    if (t < 16) {
        float cnt = (float)(s1 - s0);
        out[g * 16 + t] = sm[t] / fmaxf(cnt, 1.f);
    }
}

extern "C" void kernel_launch(void* const* d_in, const int* in_sizes, int n_in,
                              void* d_out, int out_size, void* d_ws, size_t ws_size,
                              hipStream_t stream) {
    const float* x      = (const float*)d_in[0];
    const int*   src    = (const int*)d_in[1];
    const int*   dst    = (const int*)d_in[2];
    const int*   et     = (const int*)d_in[3];
    const int*   gid    = (const int*)d_in[4];
    const float* bases1 = (const float*)d_in[5];
    const float* coeff1 = (const float*)d_in[6];
    const float* wself1 = (const float*)d_in[7];
    const float* bias1  = (const float*)d_in[8];
    const float* bases2 = (const float*)d_in[9];
    const float* coeff2 = (const float*)d_in[10];
    const float* wself2 = (const float*)d_in[11];
    const float* bias2  = (const float*)d_in[12];
    float* out = (float*)d_out;

    int nNodes = in_sizes[0] / 64;
    int nE = in_sizes[1];

    char* ws = (char*)d_ws;
    unsigned short* W1f = (unsigned short*)(ws);
    unsigned short* W2f = (unsigned short*)(ws + 65536);
    float* agg1 = (float*)(ws + 81920);
    float* agg2 = (float*)(ws + 25681920);
    int*   order = (int*)(ws + 32081920);
    int*   cnt   = (int*)(ws + 36082432);
    int*   offs  = (int*)(ws + 36082496);
    int*   start = (int*)(ws + 36082560);

    hipLaunchKernelGGL(k_weights, dim3(8), dim3(256), 0, stream,
                       bases1, coeff1, bases2, coeff2, W1f, W2f, cnt);
    hipLaunchKernelGGL(k_hist, dim3(256), dim3(256), 0, stream, et, cnt, nE);
    hipLaunchKernelGGL(k_scan, dim3(1), dim3(64), 0, stream, cnt, offs, order);
    hipLaunchKernelGGL(k_scatter, dim3(512), dim3(256), 0, stream,
                       et, cnt + 8, order, nE);
    hipLaunchKernelGGL(k_lin1, dim3(512), dim3(256), 0, stream,
                       x, wself1, bias1, agg1, nNodes);
    int tiles = (nE + 128) / 16;
    int eb = (tiles + 3) / 4;
    hipLaunchKernelGGL(k_edgemm1, dim3(eb), dim3(256), 0, stream,
                       x, src, dst, order, offs, W1f, agg1);
    hipLaunchKernelGGL(k_lin2, dim3(512), dim3(256), 0, stream,
                       agg1, wself2, bias2, agg2, nNodes);
    hipLaunchKernelGGL(k_edgemm2, dim3(eb), dim3(256), 0, stream,
                       agg1, src, dst, order, offs, W2f, agg2);
    hipLaunchKernelGGL(k_bounds, dim3(1), dim3(128), 0, stream, gid, start, nNodes);
    hipLaunchKernelGGL(k_pool, dim3(64), dim3(256), 0, stream, agg2, start, out);
}

// Round 3
// 519.184 us; speedup vs baseline: 3.5339x; 3.5339x over previous
//
#include <hip/hip_runtime.h>

// ---------------------------------------------------------------------------
// RGCN (basis decomposition, 2 layers) + mean-pool.
// Edge phase: relation-bucketed edge tiles -> bf16 MFMA (16x16x32) -> f32
// atomic scatter. Bucketing via atomic-free counting sort (per-wave hist +
// scan + ballot-rank scatter). Self-loops via f32 readlane GEMV.
//
// ws layout (bytes):
//   W1f   us[8*4096]   @ 0           (65536)   B-frags of W1, bf16
//   W2f   us[8*1024]   @ 65536       (16384)   B-frags of W2, bf16
//   agg1  f32[N*64]    @ 81920       (25,600,000)  (becomes h in-place)
//   agg2  f32[N*16]    @ 25,681,920  (6,400,000)
//   order int[E+128]   @ 32,081,920  (4,000,512)
//   wh    int[4096*8]  @ 36,082,432  (131072)  per-wave histograms
//   wbase int[4096*8]  @ 36,213,504  (131072)  per-wave bucket bases
//   offs  int[16]      @ 36,344,576
//   start int[65]      @ 36,344,640
// total ~36.35 MB
// ---------------------------------------------------------------------------

typedef __attribute__((ext_vector_type(8))) short bf16x8;
typedef __attribute__((ext_vector_type(4))) float f32x4;

#define WCHUNK 2048

__device__ __forceinline__ unsigned short f2bf(float f) {
    unsigned u = __float_as_uint(f);
    unsigned r = u + 0x7FFFu + ((u >> 16) & 1u);   // RNE
    return (unsigned short)(r >> 16);
}

__device__ __forceinline__ float bcast(float v, int l) {
    return __uint_as_float(__builtin_amdgcn_readlane(__float_as_uint(v), l));
}

// ---- weights: W_r = sum_b coeff[r,b]*bases[b], written in B-fragment order.
// Frag convention (16x16x32 bf16): lane l holds B[k = kt*32+(l>>4)*8+j][n],
// n = nt*16+(l&15), j=0..7 contiguous.  Same k-order is used for A loads.
__global__ __launch_bounds__(256) void k_weights(
    const float* __restrict__ bases1, const float* __restrict__ coeff1,
    const float* __restrict__ bases2, const float* __restrict__ coeff2,
    unsigned short* __restrict__ W1f, unsigned short* __restrict__ W2f) {
    int r = blockIdx.x;
    int tid = threadIdx.x;
    float c1[8], c2[8];
#pragma unroll
    for (int b = 0; b < 8; ++b) { c1[b] = coeff1[r * 8 + b]; c2[b] = coeff2[r * 8 + b]; }
    for (int idx = tid; idx < 4096; idx += 256) {
        int j = idx & 7, lane = (idx >> 3) & 63, nt = (idx >> 9) & 3, kt = idx >> 11;
        int i = kt * 32 + ((lane >> 4) << 3) + j;
        int jo = nt * 16 + (lane & 15);
        float s = 0.f;
#pragma unroll
        for (int b = 0; b < 8; ++b) s = fmaf(c1[b], bases1[b * 4096 + i * 64 + jo], s);
        W1f[r * 4096 + idx] = f2bf(s);
    }
    for (int idx = tid; idx < 1024; idx += 256) {
        int j = idx & 7, lane = (idx >> 3) & 63, kt = idx >> 9;
        int i = kt * 32 + ((lane >> 4) << 3) + j;
        int jo = lane & 15;
        float s = 0.f;
#pragma unroll
        for (int b = 0; b < 8; ++b) s = fmaf(c2[b], bases2[b * 1024 + i * 16 + jo], s);
        W2f[r * 1024 + idx] = f2bf(s);
    }
}

// ---- per-wave relation histograms (no atomics)
__global__ __launch_bounds__(256) void k_whist(
    const int* __restrict__ et, int* __restrict__ wh, int nE, int nWaves) {
    int wid = (int)((blockIdx.x * blockDim.x + threadIdx.x) >> 6);
    int lane = threadIdx.x & 63;
    if (wid >= nWaves) return;
    int e0 = wid * WCHUNK, e1 = min(e0 + WCHUNK, nE);
    int c0 = 0, c1 = 0, c2 = 0, c3 = 0, c4 = 0, c5 = 0, c6 = 0, c7 = 0;
    for (int c = e0; c < e1; c += 64) {
        int e = c + lane;
        int r = (e < e1) ? et[e] : -1;
        c0 += __popcll(__ballot(r == 0)); c1 += __popcll(__ballot(r == 1));
        c2 += __popcll(__ballot(r == 2)); c3 += __popcll(__ballot(r == 3));
        c4 += __popcll(__ballot(r == 4)); c5 += __popcll(__ballot(r == 5));
        c6 += __popcll(__ballot(r == 6)); c7 += __popcll(__ballot(r == 7));
    }
    int v = c0;
    if (lane == 1) v = c1; if (lane == 2) v = c2; if (lane == 3) v = c3;
    if (lane == 4) v = c4; if (lane == 5) v = c5; if (lane == 6) v = c6;
    if (lane == 7) v = c7;
    if (lane < 8) wh[wid * 8 + lane] = v;
}

// ---- scan: per-relation totals -> 16-aligned offsets -> per-wave bases
__global__ void k_scan2(const int* __restrict__ wh, int* __restrict__ wbase,
                        int* __restrict__ offs, int* __restrict__ order,
                        int nWaves) {
    __shared__ int tot[8];
    __shared__ int off[9];
    int r = threadIdx.x;
    if (r < 8) {
        int s = 0;
        for (int w = 0; w < nWaves; ++w) { wbase[w * 8 + r] = s; s += wh[w * 8 + r]; }
        tot[r] = s;
    }
    __syncthreads();
    if (r == 0) {
        int o = 0;
        for (int q = 0; q < 8; ++q) { off[q] = o; offs[q] = o; o += (tot[q] + 15) & ~15; }
        off[8] = o; offs[8] = o;
    }
    __syncthreads();
    if (r < 8) {
        int base = off[r];
        for (int w = 0; w < nWaves; ++w) wbase[w * 8 + r] += base;
        for (int p = base + tot[r]; p < off[r + 1]; ++p) order[p] = -1;
    }
}

// ---- scatter edge ids into relation buckets (register cursors, no atomics)
__global__ __launch_bounds__(256) void k_scatter2(
    const int* __restrict__ et, const int* __restrict__ wbase,
    int* __restrict__ order, int nE, int nWaves) {
    int wid = (int)((blockIdx.x * blockDim.x + threadIdx.x) >> 6);
    int lane = threadIdx.x & 63;
    if (wid >= nWaves) return;
    int e0 = wid * WCHUNK, e1 = min(e0 + WCHUNK, nE);
    int cu0 = wbase[wid * 8 + 0], cu1 = wbase[wid * 8 + 1];
    int cu2 = wbase[wid * 8 + 2], cu3 = wbase[wid * 8 + 3];
    int cu4 = wbase[wid * 8 + 4], cu5 = wbase[wid * 8 + 5];
    int cu6 = wbase[wid * 8 + 6], cu7 = wbase[wid * 8 + 7];
    unsigned long long below = (1ull << lane) - 1ull;
    for (int c = e0; c < e1; c += 64) {
        int e = c + lane;
        int r = (e < e1) ? et[e] : -1;
        int pos = -1;
#define DOREL(RR, CU) { unsigned long long m = __ballot(r == RR); \
        if (r == RR) pos = CU + __popcll(m & below); CU += __popcll(m); }
        DOREL(0, cu0) DOREL(1, cu1) DOREL(2, cu2) DOREL(3, cu3)
        DOREL(4, cu4) DOREL(5, cu5) DOREL(6, cu6) DOREL(7, cu7)
#undef DOREL
        if (pos >= 0) order[pos] = e;
    }
}

// ---- self-loop layer1: agg1[n][j] = bias1[j] + sum_i x[n][i]*wself1[i][j]
__global__ __launch_bounds__(256) void k_lin1(
    const float* __restrict__ x, const float* __restrict__ wself,
    const float* __restrict__ bias, float* __restrict__ agg, int nNodes) {
    int lane = threadIdx.x & 63;
    int gw = (int)((blockIdx.x * blockDim.x + threadIdx.x) >> 6);
    int nW = (int)((gridDim.x * blockDim.x) >> 6);
    float w[64];
#pragma unroll
    for (int i = 0; i < 64; ++i) w[i] = wself[i * 64 + lane];
    float bj = bias[lane];
    for (int n = gw; n < nNodes; n += nW) {
        float xv = x[n * 64 + lane];
        float a0 = 0.f, a1 = 0.f, a2 = 0.f, a3 = 0.f;
#pragma unroll
        for (int i = 0; i < 64; i += 4) {
            a0 = fmaf(bcast(xv, i + 0), w[i + 0], a0);
            a1 = fmaf(bcast(xv, i + 1), w[i + 1], a1);
            a2 = fmaf(bcast(xv, i + 2), w[i + 2], a2);
            a3 = fmaf(bcast(xv, i + 3), w[i + 3], a3);
        }
        agg[n * 64 + lane] = bj + ((a0 + a1) + (a2 + a3));
    }
}

// ---- edge GEMM layer1: 16-edge tiles, A = gathered x rows (bf16), B = W_r
__global__ __launch_bounds__(256) void k_edgemm1(
    const float* __restrict__ x, const int* __restrict__ src,
    const int* __restrict__ dst, const int* __restrict__ order,
    const int* __restrict__ offs, const unsigned short* __restrict__ W1f,
    float* __restrict__ agg) {
    int lane = threadIdx.x & 63;
    int wid = (int)(threadIdx.x >> 6);
    int tile = blockIdx.x * 4 + wid;
    int t16 = tile * 16;
    if (t16 >= offs[8]) return;
    int r = 0;
#pragma unroll
    for (int q = 1; q < 8; ++q) r += (t16 >= offs[q]);
    const unsigned short* Wf = W1f + r * 4096;
    bf16x8 b[2][4];
#pragma unroll
    for (int kt = 0; kt < 2; ++kt)
#pragma unroll
        for (int nt = 0; nt < 4; ++nt)
            b[kt][nt] = *(const bf16x8*)(Wf + (kt * 4 + nt) * 512 + lane * 8);
    int idxA = order[t16 + (lane & 15)];
    int sA = idxA >= 0 ? src[idxA] : 0;
    const float* xrow = x + (size_t)sA * 64 + ((lane >> 4) << 3);
    bf16x8 a[2];
#pragma unroll
    for (int kt = 0; kt < 2; ++kt) {
        f32x4 u0 = *(const f32x4*)(xrow + kt * 32);
        f32x4 u1 = *(const f32x4*)(xrow + kt * 32 + 4);
        bf16x8 t;
        t[0] = (short)f2bf(u0[0]); t[1] = (short)f2bf(u0[1]);
        t[2] = (short)f2bf(u0[2]); t[3] = (short)f2bf(u0[3]);
        t[4] = (short)f2bf(u1[0]); t[5] = (short)f2bf(u1[1]);
        t[6] = (short)f2bf(u1[2]); t[7] = (short)f2bf(u1[3]);
        a[kt] = t;
    }
    f32x4 z = {0.f, 0.f, 0.f, 0.f};
    f32x4 acc[4] = {z, z, z, z};
#pragma unroll
    for (int kt = 0; kt < 2; ++kt)
#pragma unroll
        for (int nt = 0; nt < 4; ++nt)
            acc[nt] = __builtin_amdgcn_mfma_f32_16x16x32_bf16(a[kt], b[kt][nt], acc[nt], 0, 0, 0);
#pragma unroll
    for (int reg = 0; reg < 4; ++reg) {
        int row = ((lane >> 4) << 2) + reg;
        int idxD = order[t16 + row];
        if (idxD < 0) continue;
        int d = dst[idxD];
        float* ap = agg + (size_t)d * 64 + (lane & 15);
        atomicAdd(ap + 0,  acc[0][reg]);
        atomicAdd(ap + 16, acc[1][reg]);
        atomicAdd(ap + 32, acc[2][reg]);
        atomicAdd(ap + 48, acc[3][reg]);
    }
}

// ---- relu + self-loop layer2; h kept f32 in-place in agg1
__global__ __launch_bounds__(256) void k_lin2(
    float* __restrict__ agg1, const float* __restrict__ wself,
    const float* __restrict__ bias, float* __restrict__ agg2, int nNodes) {
    int lane = threadIdx.x & 63;
    int j = lane & 15;
    int gw = (int)((blockIdx.x * blockDim.x + threadIdx.x) >> 6);
    int nW = (int)((gridDim.x * blockDim.x) >> 6);
    float w[64];
#pragma unroll
    for (int i = 0; i < 64; ++i) w[i] = wself[i * 16 + j];
    float bj = bias[j];
    for (int n = gw; n < nNodes; n += nW) {
        float hv = fmaxf(agg1[n * 64 + lane], 0.f);
        agg1[n * 64 + lane] = hv;
        float a0 = 0.f, a1 = 0.f, a2 = 0.f, a3 = 0.f;
#pragma unroll
        for (int i = 0; i < 64; i += 4) {
            a0 = fmaf(bcast(hv, i + 0), w[i + 0], a0);
            a1 = fmaf(bcast(hv, i + 1), w[i + 1], a1);
            a2 = fmaf(bcast(hv, i + 2), w[i + 2], a2);
            a3 = fmaf(bcast(hv, i + 3), w[i + 3], a3);
        }
        if (lane < 16) agg2[n * 16 + lane] = bj + ((a0 + a1) + (a2 + a3));
    }
}

// ---- edge GEMM layer2: N=16 output cols
__global__ __launch_bounds__(256) void k_edgemm2(
    const float* __restrict__ h, const int* __restrict__ src,
    const int* __restrict__ dst, const int* __restrict__ order,
    const int* __restrict__ offs, const unsigned short* __restrict__ W2f,
    float* __restrict__ agg2) {
    int lane = threadIdx.x & 63;
    int wid = (int)(threadIdx.x >> 6);
    int tile = blockIdx.x * 4 + wid;
    int t16 = tile * 16;
    if (t16 >= offs[8]) return;
    int r = 0;
#pragma unroll
    for (int q = 1; q < 8; ++q) r += (t16 >= offs[q]);
    const unsigned short* Wf = W2f + r * 1024;
    bf16x8 b[2];
    b[0] = *(const bf16x8*)(Wf + lane * 8);
    b[1] = *(const bf16x8*)(Wf + 512 + lane * 8);
    int idxA = order[t16 + (lane & 15)];
    int sA = idxA >= 0 ? src[idxA] : 0;
    const float* hrow = h + (size_t)sA * 64 + ((lane >> 4) << 3);
    bf16x8 a[2];
#pragma unroll
    for (int kt = 0; kt < 2; ++kt) {
        f32x4 u0 = *(const f32x4*)(hrow + kt * 32);
        f32x4 u1 = *(const f32x4*)(hrow + kt * 32 + 4);
        bf16x8 t;
        t[0] = (short)f2bf(u0[0]); t[1] = (short)f2bf(u0[1]);
        t[2] = (short)f2bf(u0[2]); t[3] = (short)f2bf(u0[3]);
        t[4] = (short)f2bf(u1[0]); t[5] = (short)f2bf(u1[1]);
        t[6] = (short)f2bf(u1[2]); t[7] = (short)f2bf(u1[3]);
        a[kt] = t;
    }
    f32x4 acc = {0.f, 0.f, 0.f, 0.f};
    acc = __builtin_amdgcn_mfma_f32_16x16x32_bf16(a[0], b[0], acc, 0, 0, 0);
    acc = __builtin_amdgcn_mfma_f32_16x16x32_bf16(a[1], b[1], acc, 0, 0, 0);
#pragma unroll
    for (int reg = 0; reg < 4; ++reg) {
        int row = ((lane >> 4) << 2) + reg;
        int idxD = order[t16 + row];
        if (idxD < 0) continue;
        int d = dst[idxD];
        atomicAdd(agg2 + (size_t)d * 16 + (lane & 15), acc[reg]);
    }
}

__global__ void k_bounds(const int* __restrict__ gid, int* __restrict__ start, int nNodes) {
    int t = blockIdx.x * blockDim.x + threadIdx.x;
    if (t > 64) return;
    int lo = 0, hi = nNodes;
    while (lo < hi) {
        int mid = (lo + hi) >> 1;
        if (gid[mid] < t) lo = mid + 1; else hi = mid;
    }
    start[t] = lo;
}

__global__ __launch_bounds__(256) void k_pool(
    const float* __restrict__ agg2, const int* __restrict__ start,
    float* __restrict__ out) {
    __shared__ float sm[256];
    int g = blockIdx.x;
    int t = threadIdx.x;
    int c = t & 15, idx = t >> 4;
    int s0 = start[g], s1 = start[g + 1];
    float acc = 0.f;
    for (int n = s0 + idx; n < s1; n += 16) acc += fmaxf(agg2[n * 16 + c], 0.f);
    sm[t] = acc;
    __syncthreads();
#pragma unroll
    for (int off = 128; off >= 16; off >>= 1) {
        if (t < off) sm[t] += sm[t + off];
        __syncthreads();
    }
    if (t < 16) {
        float cnt = (float)(s1 - s0);
        out[g * 16 + t] = sm[t] / fmaxf(cnt, 1.f);
    }
}

extern "C" void kernel_launch(void* const* d_in, const int* in_sizes, int n_in,
                              void* d_out, int out_size, void* d_ws, size_t ws_size,
                              hipStream_t stream) {
    const float* x      = (const float*)d_in[0];
    const int*   src    = (const int*)d_in[1];
    const int*   dst    = (const int*)d_in[2];
    const int*   et     = (const int*)d_in[3];
    const int*   gid    = (const int*)d_in[4];
    const float* bases1 = (const float*)d_in[5];
    const float* coeff1 = (const float*)d_in[6];
    const float* wself1 = (const float*)d_in[7];
    const float* bias1  = (const float*)d_in[8];
    const float* bases2 = (const float*)d_in[9];
    const float* coeff2 = (const float*)d_in[10];
    const float* wself2 = (const float*)d_in[11];
    const float* bias2  = (const float*)d_in[12];
    float* out = (float*)d_out;

    int nNodes = in_sizes[0] / 64;
    int nE = in_sizes[1];

    char* ws = (char*)d_ws;
    unsigned short* W1f = (unsigned short*)(ws);
    unsigned short* W2f = (unsigned short*)(ws + 65536);
    float* agg1  = (float*)(ws + 81920);
    float* agg2  = (float*)(ws + 25681920);
    int*   order = (int*)(ws + 32081920);
    int*   wh    = (int*)(ws + 36082432);
    int*   wbase = (int*)(ws + 36213504);
    int*   offs  = (int*)(ws + 36344576);
    int*   start = (int*)(ws + 36344640);

    int nWaves = (nE + WCHUNK - 1) / WCHUNK;
    int hb = (nWaves * 64 + 255) / 256;

    hipLaunchKernelGGL(k_weights, dim3(8), dim3(256), 0, stream,
                       bases1, coeff1, bases2, coeff2, W1f, W2f);
    hipLaunchKernelGGL(k_whist, dim3(hb), dim3(256), 0, stream, et, wh, nE, nWaves);
    hipLaunchKernelGGL(k_scan2, dim3(1), dim3(64), 0, stream,
                       wh, wbase, offs, order, nWaves);
    hipLaunchKernelGGL(k_scatter2, dim3(hb), dim3(256), 0, stream,
                       et, wbase, order, nE, nWaves);
    hipLaunchKernelGGL(k_lin1, dim3(512), dim3(256), 0, stream,
                       x, wself1, bias1, agg1, nNodes);
    int tiles = (nE + 128) / 16;
    int eb = (tiles + 3) / 4;
    hipLaunchKernelGGL(k_edgemm1, dim3(eb), dim3(256), 0, stream,
                       x, src, dst, order, offs, W1f, agg1);
    hipLaunchKernelGGL(k_lin2, dim3(512), dim3(256), 0, stream,
                       agg1, wself2, bias2, agg2, nNodes);
    hipLaunchKernelGGL(k_edgemm2, dim3(eb), dim3(256), 0, stream,
                       agg1, src, dst, order, offs, W2f, agg2);
    hipLaunchKernelGGL(k_bounds, dim3(1), dim3(128), 0, stream, gid, start, nNodes);
    hipLaunchKernelGGL(k_pool, dim3(64), dim3(256), 0, stream, agg2, start, out);
}

// Round 4
// 515.819 us; speedup vs baseline: 3.5570x; 1.0065x over previous
//
#include <hip/hip_runtime.h>

// ---------------------------------------------------------------------------
// RGCN (basis decomposition, 2 layers) + mean-pool.
// Edge phase: relation-bucketed 16-edge tiles -> bf16 MFMA (16x16x32) ->
// packed-bf16 atomic scatter (global_atomic_pk_add_bf16). Node features bf16
// end-to-end on the message path. Bucketing via atomic-free counting sort.
//
// ws layout (bytes):
//   W1f   us[8*4096]   @ 0           (65536)   B-frags of W1, bf16
//   W2f   us[8*1024]   @ 65536       (16384)   B-frags of W2, bf16
//   xbf   us[N*64]     @ 81920       (12,800,000)  x cast to bf16
//   agg1  us[N*64]     @ 12,881,920  (12,800,000)  bf16 agg (becomes h)
//   agg2  us[N*16]     @ 25,681,920  (3,200,000)   bf16 agg layer2
//   order int[E+128]   @ 28,881,920  (4,000,512)
//   wh    int[4096*8]  @ 32,882,432  (131072)
//   wbase int[4096*8]  @ 33,013,504  (131072)
//   offs  int[16]      @ 33,144,576
//   start int[65]      @ 33,144,640
// total ~33.15 MB
// ---------------------------------------------------------------------------

typedef __attribute__((ext_vector_type(8))) short bf16x8;
typedef __attribute__((ext_vector_type(4))) float f32x4;

#define WCHUNK 2048

__device__ __forceinline__ unsigned short f2bf(float f) {
    unsigned u = __float_as_uint(f);
    unsigned r = u + 0x7FFFu + ((u >> 16) & 1u);   // RNE
    return (unsigned short)(r >> 16);
}

__device__ __forceinline__ float bf2f(unsigned short u) {
    return __uint_as_float(((unsigned)u) << 16);
}

__device__ __forceinline__ float bcast(float v, int l) {
    return __uint_as_float(__builtin_amdgcn_readlane(__float_as_uint(v), l));
}

// fire-and-forget packed bf16 atomic add (2 adjacent bf16 at 4B-aligned addr)
__device__ __forceinline__ void pkAddBf16(unsigned short* addr, unsigned pk) {
    asm volatile("global_atomic_pk_add_bf16 %0, %1, off"
                 :: "v"((unsigned long long)(size_t)addr), "v"(pk));
}

// ---- weights: W_r = sum_b coeff[r,b]*bases[b], written in B-fragment order.
// Frag convention (16x16x32 bf16): lane l holds B[k = kt*32+(l>>4)*8+j][n],
// n = nt*16+(l&15), j=0..7 contiguous.  Same k-order is used for A loads.
__global__ __launch_bounds__(256) void k_weights(
    const float* __restrict__ bases1, const float* __restrict__ coeff1,
    const float* __restrict__ bases2, const float* __restrict__ coeff2,
    unsigned short* __restrict__ W1f, unsigned short* __restrict__ W2f) {
    int r = blockIdx.x;
    int tid = threadIdx.x;
    float c1[8], c2[8];
#pragma unroll
    for (int b = 0; b < 8; ++b) { c1[b] = coeff1[r * 8 + b]; c2[b] = coeff2[r * 8 + b]; }
    for (int idx = tid; idx < 4096; idx += 256) {
        int j = idx & 7, lane = (idx >> 3) & 63, nt = (idx >> 9) & 3, kt = idx >> 11;
        int i = kt * 32 + ((lane >> 4) << 3) + j;
        int jo = nt * 16 + (lane & 15);
        float s = 0.f;
#pragma unroll
        for (int b = 0; b < 8; ++b) s = fmaf(c1[b], bases1[b * 4096 + i * 64 + jo], s);
        W1f[r * 4096 + idx] = f2bf(s);
    }
    for (int idx = tid; idx < 1024; idx += 256) {
        int j = idx & 7, lane = (idx >> 3) & 63, kt = idx >> 9;
        int i = kt * 32 + ((lane >> 4) << 3) + j;
        int jo = lane & 15;
        float s = 0.f;
#pragma unroll
        for (int b = 0; b < 8; ++b) s = fmaf(c2[b], bases2[b * 1024 + i * 16 + jo], s);
        W2f[r * 1024 + idx] = f2bf(s);
    }
}

// ---- cast x to bf16 rows
__global__ __launch_bounds__(256) void k_xcast(
    const float* __restrict__ x, unsigned short* __restrict__ xbf, int n8) {
    int stride = gridDim.x * blockDim.x;
    for (int i = blockIdx.x * blockDim.x + threadIdx.x; i < n8; i += stride) {
        f32x4 u0 = *(const f32x4*)(x + (size_t)i * 8);
        f32x4 u1 = *(const f32x4*)(x + (size_t)i * 8 + 4);
        bf16x8 t;
        t[0] = (short)f2bf(u0[0]); t[1] = (short)f2bf(u0[1]);
        t[2] = (short)f2bf(u0[2]); t[3] = (short)f2bf(u0[3]);
        t[4] = (short)f2bf(u1[0]); t[5] = (short)f2bf(u1[1]);
        t[6] = (short)f2bf(u1[2]); t[7] = (short)f2bf(u1[3]);
        *(bf16x8*)(xbf + (size_t)i * 8) = t;
    }
}

// ---- per-wave relation histograms (no atomics)
__global__ __launch_bounds__(256) void k_whist(
    const int* __restrict__ et, int* __restrict__ wh, int nE, int nWaves) {
    int wid = (int)((blockIdx.x * blockDim.x + threadIdx.x) >> 6);
    int lane = threadIdx.x & 63;
    if (wid >= nWaves) return;
    int e0 = wid * WCHUNK, e1 = min(e0 + WCHUNK, nE);
    int c0 = 0, c1 = 0, c2 = 0, c3 = 0, c4 = 0, c5 = 0, c6 = 0, c7 = 0;
    for (int c = e0; c < e1; c += 64) {
        int e = c + lane;
        int r = (e < e1) ? et[e] : -1;
        c0 += __popcll(__ballot(r == 0)); c1 += __popcll(__ballot(r == 1));
        c2 += __popcll(__ballot(r == 2)); c3 += __popcll(__ballot(r == 3));
        c4 += __popcll(__ballot(r == 4)); c5 += __popcll(__ballot(r == 5));
        c6 += __popcll(__ballot(r == 6)); c7 += __popcll(__ballot(r == 7));
    }
    int v = c0;
    if (lane == 1) v = c1; if (lane == 2) v = c2; if (lane == 3) v = c3;
    if (lane == 4) v = c4; if (lane == 5) v = c5; if (lane == 6) v = c6;
    if (lane == 7) v = c7;
    if (lane < 8) wh[wid * 8 + lane] = v;
}

// ---- scan: per-relation totals -> 16-aligned offsets -> per-wave bases
__global__ void k_scan2(const int* __restrict__ wh, int* __restrict__ wbase,
                        int* __restrict__ offs, int* __restrict__ order,
                        int nWaves) {
    __shared__ int tot[8];
    __shared__ int off[9];
    int r = threadIdx.x;
    if (r < 8) {
        int s = 0;
        for (int w = 0; w < nWaves; ++w) { wbase[w * 8 + r] = s; s += wh[w * 8 + r]; }
        tot[r] = s;
    }
    __syncthreads();
    if (r == 0) {
        int o = 0;
        for (int q = 0; q < 8; ++q) { off[q] = o; offs[q] = o; o += (tot[q] + 15) & ~15; }
        off[8] = o; offs[8] = o;
    }
    __syncthreads();
    if (r < 8) {
        int base = off[r];
        for (int w = 0; w < nWaves; ++w) wbase[w * 8 + r] += base;
        for (int p = base + tot[r]; p < off[r + 1]; ++p) order[p] = -1;
    }
}

// ---- scatter edge ids into relation buckets (register cursors, no atomics)
__global__ __launch_bounds__(256) void k_scatter2(
    const int* __restrict__ et, const int* __restrict__ wbase,
    int* __restrict__ order, int nE, int nWaves) {
    int wid = (int)((blockIdx.x * blockDim.x + threadIdx.x) >> 6);
    int lane = threadIdx.x & 63;
    if (wid >= nWaves) return;
    int e0 = wid * WCHUNK, e1 = min(e0 + WCHUNK, nE);
    int cu0 = wbase[wid * 8 + 0], cu1 = wbase[wid * 8 + 1];
    int cu2 = wbase[wid * 8 + 2], cu3 = wbase[wid * 8 + 3];
    int cu4 = wbase[wid * 8 + 4], cu5 = wbase[wid * 8 + 5];
    int cu6 = wbase[wid * 8 + 6], cu7 = wbase[wid * 8 + 7];
    unsigned long long below = (1ull << lane) - 1ull;
    for (int c = e0; c < e1; c += 64) {
        int e = c + lane;
        int r = (e < e1) ? et[e] : -1;
        int pos = -1;
#define DOREL(RR, CU) { unsigned long long m = __ballot(r == RR); \
        if (r == RR) pos = CU + __popcll(m & below); CU += __popcll(m); }
        DOREL(0, cu0) DOREL(1, cu1) DOREL(2, cu2) DOREL(3, cu3)
        DOREL(4, cu4) DOREL(5, cu5) DOREL(6, cu6) DOREL(7, cu7)
#undef DOREL
        if (pos >= 0) order[pos] = e;
    }
}

// ---- self-loop layer1: agg1[n][j] = bf16(bias1[j] + sum_i x[n][i]*wself1[i][j])
__global__ __launch_bounds__(256) void k_lin1(
    const float* __restrict__ x, const float* __restrict__ wself,
    const float* __restrict__ bias, unsigned short* __restrict__ agg, int nNodes) {
    int lane = threadIdx.x & 63;
    int gw = (int)((blockIdx.x * blockDim.x + threadIdx.x) >> 6);
    int nW = (int)((gridDim.x * blockDim.x) >> 6);
    float w[64];
#pragma unroll
    for (int i = 0; i < 64; ++i) w[i] = wself[i * 64 + lane];
    float bj = bias[lane];
    for (int n = gw; n < nNodes; n += nW) {
        float xv = x[n * 64 + lane];
        float a0 = 0.f, a1 = 0.f, a2 = 0.f, a3 = 0.f;
#pragma unroll
        for (int i = 0; i < 64; i += 4) {
            a0 = fmaf(bcast(xv, i + 0), w[i + 0], a0);
            a1 = fmaf(bcast(xv, i + 1), w[i + 1], a1);
            a2 = fmaf(bcast(xv, i + 2), w[i + 2], a2);
            a3 = fmaf(bcast(xv, i + 3), w[i + 3], a3);
        }
        agg[(size_t)n * 64 + lane] = f2bf(bj + ((a0 + a1) + (a2 + a3)));
    }
}

// ---- edge GEMM layer1: 16-edge tiles, A = gathered xbf rows, B = W_r frags
__global__ __launch_bounds__(256) void k_edgemm1(
    const unsigned short* __restrict__ xbf, const int* __restrict__ src,
    const int* __restrict__ dst, const int* __restrict__ order,
    const int* __restrict__ offs, const unsigned short* __restrict__ W1f,
    unsigned short* __restrict__ agg) {
    int lane = threadIdx.x & 63;
    int wid = (int)(threadIdx.x >> 6);
    int tile = blockIdx.x * 4 + wid;
    int t16 = tile * 16;
    if (t16 >= offs[8]) return;
    int r = 0;
#pragma unroll
    for (int q = 1; q < 8; ++q) r += (t16 >= offs[q]);
    const unsigned short* Wf = W1f + r * 4096;
    bf16x8 b[2][4];
#pragma unroll
    for (int kt = 0; kt < 2; ++kt)
#pragma unroll
        for (int nt = 0; nt < 4; ++nt)
            b[kt][nt] = *(const bf16x8*)(Wf + (kt * 4 + nt) * 512 + lane * 8);
    int idxA = order[t16 + (lane & 15)];
    int sA = idxA >= 0 ? src[idxA] : 0;
    const unsigned short* xrow = xbf + (size_t)sA * 64 + ((lane >> 4) << 3);
    bf16x8 a[2];
    a[0] = *(const bf16x8*)(xrow);
    a[1] = *(const bf16x8*)(xrow + 32);
    f32x4 z = {0.f, 0.f, 0.f, 0.f};
    f32x4 acc[4] = {z, z, z, z};
#pragma unroll
    for (int kt = 0; kt < 2; ++kt)
#pragma unroll
        for (int nt = 0; nt < 4; ++nt)
            acc[nt] = __builtin_amdgcn_mfma_f32_16x16x32_bf16(a[kt], b[kt][nt], acc[nt], 0, 0, 0);
    const int even = !(lane & 1);
#pragma unroll
    for (int reg = 0; reg < 4; ++reg) {
        int row = ((lane >> 4) << 2) + reg;
        int idxD = order[t16 + row];
        if (idxD < 0) continue;                     // pair-uniform
        int d = dst[idxD];
        unsigned short* ap = agg + (size_t)d * 64 + (lane & 14);
#pragma unroll
        for (int nt = 0; nt < 4; ++nt) {
            float mine = acc[nt][reg];
            float oth = __shfl_xor(mine, 1, 64);
            unsigned pk = even ? ((unsigned)f2bf(mine) | ((unsigned)f2bf(oth) << 16))
                               : ((unsigned)f2bf(oth) | ((unsigned)f2bf(mine) << 16));
            if (even ? (nt < 2) : (nt >= 2))
                pkAddBf16(ap + nt * 16, pk);
        }
    }
}

// ---- relu (in-place bf16) + self-loop layer2 -> agg2 init (bf16)
__global__ __launch_bounds__(256) void k_lin2(
    unsigned short* __restrict__ agg1, const float* __restrict__ wself,
    const float* __restrict__ bias, unsigned short* __restrict__ agg2, int nNodes) {
    int lane = threadIdx.x & 63;
    int j = lane & 15;
    int gw = (int)((blockIdx.x * blockDim.x + threadIdx.x) >> 6);
    int nW = (int)((gridDim.x * blockDim.x) >> 6);
    float w[64];
#pragma unroll
    for (int i = 0; i < 64; ++i) w[i] = wself[i * 16 + j];
    float bj = bias[j];
    for (int n = gw; n < nNodes; n += nW) {
        unsigned short raw = agg1[(size_t)n * 64 + lane];
        unsigned short rbf = (raw & 0x8000u) ? (unsigned short)0 : raw;
        agg1[(size_t)n * 64 + lane] = rbf;          // h (relu'd) in place
        float hv = bf2f(rbf);
        float a0 = 0.f, a1 = 0.f, a2 = 0.f, a3 = 0.f;
#pragma unroll
        for (int i = 0; i < 64; i += 4) {
            a0 = fmaf(bcast(hv, i + 0), w[i + 0], a0);
            a1 = fmaf(bcast(hv, i + 1), w[i + 1], a1);
            a2 = fmaf(bcast(hv, i + 2), w[i + 2], a2);
            a3 = fmaf(bcast(hv, i + 3), w[i + 3], a3);
        }
        if (lane < 16) agg2[(size_t)n * 16 + lane] = f2bf(bj + ((a0 + a1) + (a2 + a3)));
    }
}

// ---- edge GEMM layer2: N=16 output cols, h gathered bf16
__global__ __launch_bounds__(256) void k_edgemm2(
    const unsigned short* __restrict__ h, const int* __restrict__ src,
    const int* __restrict__ dst, const int* __restrict__ order,
    const int* __restrict__ offs, const unsigned short* __restrict__ W2f,
    unsigned short* __restrict__ agg2) {
    int lane = threadIdx.x & 63;
    int wid = (int)(threadIdx.x >> 6);
    int tile = blockIdx.x * 4 + wid;
    int t16 = tile * 16;
    if (t16 >= offs[8]) return;
    int r = 0;
#pragma unroll
    for (int q = 1; q < 8; ++q) r += (t16 >= offs[q]);
    const unsigned short* Wf = W2f + r * 1024;
    bf16x8 b[2];
    b[0] = *(const bf16x8*)(Wf + lane * 8);
    b[1] = *(const bf16x8*)(Wf + 512 + lane * 8);
    int idxA = order[t16 + (lane & 15)];
    int sA = idxA >= 0 ? src[idxA] : 0;
    const unsigned short* hrow = h + (size_t)sA * 64 + ((lane >> 4) << 3);
    bf16x8 a[2];
    a[0] = *(const bf16x8*)(hrow);
    a[1] = *(const bf16x8*)(hrow + 32);
    f32x4 acc = {0.f, 0.f, 0.f, 0.f};
    acc = __builtin_amdgcn_mfma_f32_16x16x32_bf16(a[0], b[0], acc, 0, 0, 0);
    acc = __builtin_amdgcn_mfma_f32_16x16x32_bf16(a[1], b[1], acc, 0, 0, 0);
    const int even = !(lane & 1);
#pragma unroll
    for (int reg = 0; reg < 4; ++reg) {
        int row = ((lane >> 4) << 2) + reg;
        int idxD = order[t16 + row];
        if (idxD < 0) continue;                     // pair-uniform
        float mine = acc[reg];
        float oth = __shfl_xor(mine, 1, 64);
        int d = dst[idxD];
        unsigned pk = even ? ((unsigned)f2bf(mine) | ((unsigned)f2bf(oth) << 16))
                           : ((unsigned)f2bf(oth) | ((unsigned)f2bf(mine) << 16));
        if (even ? (reg < 2) : (reg >= 2))
            pkAddBf16(agg2 + (size_t)d * 16 + (lane & 14), pk);
    }
}

__global__ void k_bounds(const int* __restrict__ gid, int* __restrict__ start, int nNodes) {
    int t = blockIdx.x * blockDim.x + threadIdx.x;
    if (t > 64) return;
    int lo = 0, hi = nNodes;
    while (lo < hi) {
        int mid = (lo + hi) >> 1;
        if (gid[mid] < t) lo = mid + 1; else hi = mid;
    }
    start[t] = lo;
}

__global__ __launch_bounds__(256) void k_pool(
    const unsigned short* __restrict__ agg2, const int* __restrict__ start,
    float* __restrict__ out) {
    __shared__ float sm[256];
    int g = blockIdx.x;
    int t = threadIdx.x;
    int c = t & 15, idx = t >> 4;
    int s0 = start[g], s1 = start[g + 1];
    float acc = 0.f;
    for (int n = s0 + idx; n < s1; n += 16) acc += fmaxf(bf2f(agg2[(size_t)n * 16 + c]), 0.f);
    sm[t] = acc;
    __syncthreads();
#pragma unroll
    for (int off = 128; off >= 16; off >>= 1) {
        if (t < off) sm[t] += sm[t + off];
        __syncthreads();
    }
    if (t < 16) {
        float cnt = (float)(s1 - s0);
        out[g * 16 + t] = sm[t] / fmaxf(cnt, 1.f);
    }
}

extern "C" void kernel_launch(void* const* d_in, const int* in_sizes, int n_in,
                              void* d_out, int out_size, void* d_ws, size_t ws_size,
                              hipStream_t stream) {
    const float* x      = (const float*)d_in[0];
    const int*   src    = (const int*)d_in[1];
    const int*   dst    = (const int*)d_in[2];
    const int*   et     = (const int*)d_in[3];
    const int*   gid    = (const int*)d_in[4];
    const float* bases1 = (const float*)d_in[5];
    const float* coeff1 = (const float*)d_in[6];
    const float* wself1 = (const float*)d_in[7];
    const float* bias1  = (const float*)d_in[8];
    const float* bases2 = (const float*)d_in[9];
    const float* coeff2 = (const float*)d_in[10];
    const float* wself2 = (const float*)d_in[11];
    const float* bias2  = (const float*)d_in[12];
    float* out = (float*)d_out;

    int nNodes = in_sizes[0] / 64;
    int nE = in_sizes[1];

    char* ws = (char*)d_ws;
    unsigned short* W1f  = (unsigned short*)(ws);
    unsigned short* W2f  = (unsigned short*)(ws + 65536);
    unsigned short* xbf  = (unsigned short*)(ws + 81920);
    unsigned short* agg1 = (unsigned short*)(ws + 12881920);
    unsigned short* agg2 = (unsigned short*)(ws + 25681920);
    int*   order = (int*)(ws + 28881920);
    int*   wh    = (int*)(ws + 32882432);
    int*   wbase = (int*)(ws + 33013504);
    int*   offs  = (int*)(ws + 33144576);
    int*   start = (int*)(ws + 33144640);

    int nWaves = (nE + WCHUNK - 1) / WCHUNK;
    int hb = (nWaves * 64 + 255) / 256;

    hipLaunchKernelGGL(k_weights, dim3(8), dim3(256), 0, stream,
                       bases1, coeff1, bases2, coeff2, W1f, W2f);
    hipLaunchKernelGGL(k_xcast, dim3(2048), dim3(256), 0, stream,
                       x, xbf, nNodes * 8);
    hipLaunchKernelGGL(k_whist, dim3(hb), dim3(256), 0, stream, et, wh, nE, nWaves);
    hipLaunchKernelGGL(k_scan2, dim3(1), dim3(64), 0, stream,
                       wh, wbase, offs, order, nWaves);
    hipLaunchKernelGGL(k_scatter2, dim3(hb), dim3(256), 0, stream,
                       et, wbase, order, nE, nWaves);
    hipLaunchKernelGGL(k_lin1, dim3(512), dim3(256), 0, stream,
                       x, wself1, bias1, agg1, nNodes);
    int tiles = (nE + 128) / 16;
    int eb = (tiles + 3) / 4;
    hipLaunchKernelGGL(k_edgemm1, dim3(eb), dim3(256), 0, stream,
                       xbf, src, dst, order, offs, W1f, agg1);
    hipLaunchKernelGGL(k_lin2, dim3(512), dim3(256), 0, stream,
                       agg1, wself2, bias2, agg2, nNodes);
    hipLaunchKernelGGL(k_edgemm2, dim3(eb), dim3(256), 0, stream,
                       agg1, src, dst, order, offs, W2f, agg2);
    hipLaunchKernelGGL(k_bounds, dim3(1), dim3(128), 0, stream, gid, start, nNodes);
    hipLaunchKernelGGL(k_pool, dim3(64), dim3(256), 0, stream, agg2, start, out);
}